// Round 4
// baseline (90.014 us; speedup 1.0000x reference)
//
#include <hip/hip_runtime.h>

#define M_BASIS 100
constexpr float INV_TWO_PI = 0.15915494309189535f;
constexpr float NEG_HALF_LOG2E = -0.72134752044448170f;  // -0.5 * log2(e)

// One output float4 per thread, ZERO loops. Row = 100 floats = 25 float4s.
// Block of 256: thread t (0..249) -> grp = t/25 (row within block's 10-row
// batch), k = t%25 (float4 chunk). grid = ceil(N/10) so every thread does
// exactly one iteration -> no serial load->compute->store back-edge chain;
// ~51 queued blocks/CU of fresh TLP hide all memory latency.
__global__ __launch_bounds__(256) void cs_kernel(
    const float* __restrict__ theta,
    const float* __restrict__ basis_mu,
    const float* __restrict__ basis_sigma,
    float* __restrict__ out,
    int N)
{
    const int tid = threadIdx.x;
    if (tid >= 250) return;
    const int grp = tid / 25;        // 0..9
    const int k   = tid - grp * 25;  // 0..24
    const int j   = 4 * k;

    const int row = blockIdx.x * 10 + grp;
    if (row >= N) return;

    // --- basis params for j..j+3 (L1-resident, 2.4 KB total) ---
    float mu0[4], mu1[4];
    float s00[4], s01[4], s10[4], s11[4];
#pragma unroll
    for (int c = 0; c < 4; ++c) {
        float2 m = ((const float2*)basis_mu)[j + c];
        float4 s = ((const float4*)basis_sigma)[j + c];
        mu0[c] = m.x; mu1[c] = m.y;
        s00[c] = s.x; s01[c] = s.y; s10[c] = s.z; s11[c] = s.w;
    }

    const float* th = theta + (size_t)row * 6;
    float2 e  = *(const float2*)(th);       // eta
    float2 qa = *(const float2*)(th + 2);   // t2, t3
    float2 qb = *(const float2*)(th + 4);   // t4, t5

    // P = -2*theta[2:6]; Sigma = sym(P^-1); Mu = Sigma @ eta
    float p00 = -2.0f * qa.x, p01 = -2.0f * qa.y;
    float p10 = -2.0f * qb.x, p11 = -2.0f * qb.y;
    float inv_detP = __builtin_amdgcn_rcpf(p00 * p11 - p01 * p10);
    float S00 = p11 * inv_detP;
    float S11 = p00 * inv_detP;
    float S01 = -0.5f * (p01 + p10) * inv_detP;
    float Mu0 = S00 * e.x + S01 * e.y;
    float Mu1 = S01 * e.x + S11 * e.y;

    // 4 independent output chains (ILP) -> one dwordx4 store
    float r[4];
#pragma unroll
    for (int c = 0; c < 4; ++c) {
        float c00 = S00 + s00[c], c01 = S01 + s01[c];
        float c10 = S01 + s10[c], c11 = S11 + s11[c];
        float d0 = Mu0 - mu0[c], d1 = Mu1 - mu1[c];
        float detC = c00 * c11 - c01 * c10;
        // fold -0.5*log2(e) into the 1/detC factor: exp(-q/2) = exp2(arg)
        float invC = __builtin_amdgcn_rcpf(detC) * NEG_HALF_LOG2E;
        float arg = (d0 * (c11 * d0 - c01 * d1) + d1 * (c00 * d1 - c10 * d0)) * invC;
        r[c] = __builtin_amdgcn_exp2f(arg) * INV_TWO_PI * __builtin_amdgcn_rsqf(detC);
    }
    float4 rv = make_float4(r[0], r[1], r[2], r[3]);
    ((float4*)out)[(size_t)row * 25 + k] = rv;
}

extern "C" void kernel_launch(void* const* d_in, const int* in_sizes, int n_in,
                              void* d_out, int out_size, void* d_ws, size_t ws_size,
                              hipStream_t stream) {
    const float* theta      = (const float*)d_in[0];   // [N,6]
    const float* basis_mu   = (const float*)d_in[1];   // [M,2]
    const float* basis_sig  = (const float*)d_in[2];   // [M,2,2]
    float* out = (float*)d_out;                        // [N,M]

    int N = in_sizes[0] / 6;
    int block = 256;
    int grid = (N + 9) / 10;   // one block per 10 rows, one output float4/thread
    hipLaunchKernelGGL(cs_kernel, dim3(grid), dim3(block), 0, stream,
                       theta, basis_mu, basis_sig, out, N);
}

// Round 5
// 83.268 us; speedup vs baseline: 1.0810x; 1.0810x over previous
//
#include <hip/hip_runtime.h>

#define M_BASIS 100
constexpr float INV_TWO_PI = 0.15915494309189535f;
constexpr float NEG_HALF_LOG2E = -0.72134752044448170f;  // -0.5 * log2(e)

// Grid-stride loop (round-2 structure, best measured) + software-pipelined
// theta prefetch: iteration i issues iteration i+1's theta loads before
// computing, hiding the dependent L2/HBM latency under compute.
// Thread t (0..249): grp = t/25 (row within 10-row batch), k = t%25 (float4
// chunk of the row). Basis params for j=4k..4k+3 hoisted to registers once.
__global__ __launch_bounds__(256) void cs_kernel(
    const float* __restrict__ theta,
    const float* __restrict__ basis_mu,
    const float* __restrict__ basis_sigma,
    float* __restrict__ out,
    int N)
{
    const int tid = threadIdx.x;
    if (tid >= 250) return;
    const int grp = tid / 25;        // 0..9
    const int k   = tid - grp * 25;  // 0..24
    const int j   = 4 * k;

    // --- basis params for j..j+3, in registers for the whole kernel ---
    float mu0[4], mu1[4];
    float s00[4], s01[4], s10[4], s11[4];
#pragma unroll
    for (int c = 0; c < 4; ++c) {
        float2 m = ((const float2*)basis_mu)[j + c];
        float4 s = ((const float4*)basis_sigma)[j + c];
        mu0[c] = m.x; mu1[c] = m.y;
        s00[c] = s.x; s01[c] = s.y; s10[c] = s.z; s11[c] = s.w;
    }

    const int stride = gridDim.x * 10;
    int row = blockIdx.x * 10 + grp;
    if (row >= N) return;

    // prologue: load first row's theta
    const float* th = theta + (size_t)row * 6;
    float2 e  = *(const float2*)(th);
    float2 qa = *(const float2*)(th + 2);
    float2 qb = *(const float2*)(th + 4);

    while (row < N) {
        // --- issue NEXT iteration's theta loads first (branch-free clamp) ---
        const int nrow = row + stride;
        const int prow = (nrow < N) ? nrow : 0;   // safe in-bounds dummy
        const float* thn = theta + (size_t)prow * 6;
        float2 en  = *(const float2*)(thn);
        float2 qan = *(const float2*)(thn + 2);
        float2 qbn = *(const float2*)(thn + 4);

        // --- compute current row (overlaps with the loads above) ---
        float p00 = -2.0f * qa.x, p01 = -2.0f * qa.y;
        float p10 = -2.0f * qb.x, p11 = -2.0f * qb.y;
        float inv_detP = __builtin_amdgcn_rcpf(p00 * p11 - p01 * p10);
        float S00 = p11 * inv_detP;
        float S11 = p00 * inv_detP;
        float S01 = -0.5f * (p01 + p10) * inv_detP;
        float Mu0 = S00 * e.x + S01 * e.y;
        float Mu1 = S01 * e.x + S11 * e.y;

        float r[4];
#pragma unroll
        for (int c = 0; c < 4; ++c) {
            float c00 = S00 + s00[c], c01 = S01 + s01[c];
            float c10 = S01 + s10[c], c11 = S11 + s11[c];
            float d0 = Mu0 - mu0[c], d1 = Mu1 - mu1[c];
            float detC = c00 * c11 - c01 * c10;
            // exp(-q/2) = exp2(q * (-0.5*log2e) / detC)
            float invC = __builtin_amdgcn_rcpf(detC) * NEG_HALF_LOG2E;
            float arg = (d0 * (c11 * d0 - c01 * d1) + d1 * (c00 * d1 - c10 * d0)) * invC;
            r[c] = __builtin_amdgcn_exp2f(arg) * INV_TWO_PI * __builtin_amdgcn_rsqf(detC);
        }
        ((float4*)out)[(size_t)row * 25 + k] = make_float4(r[0], r[1], r[2], r[3]);

        // rotate pipeline registers
        row = nrow;
        e = en; qa = qan; qb = qbn;
    }
}

extern "C" void kernel_launch(void* const* d_in, const int* in_sizes, int n_in,
                              void* d_out, int out_size, void* d_ws, size_t ws_size,
                              hipStream_t stream) {
    const float* theta      = (const float*)d_in[0];   // [N,6]
    const float* basis_mu   = (const float*)d_in[1];   // [M,2]
    const float* basis_sig  = (const float*)d_in[2];   // [M,2,2]
    float* out = (float*)d_out;                        // [N,M]

    int N = in_sizes[0] / 6;
    // 2048 blocks = 8 blocks/CU fully resident (32 waves/CU); 10 rows per
    // block iteration -> ~6.4 grid-stride iterations amortize basis hoist
    // and keep the prefetch pipeline busy.
    int block = 256;
    int grid = 2048;
    hipLaunchKernelGGL(cs_kernel, dim3(grid), dim3(block), 0, stream,
                       theta, basis_mu, basis_sig, out, N);
}